// Round 4
// baseline (287.625 us; speedup 1.0000x reference)
//
#include <hip/hip_runtime.h>
#include <hip/hip_fp16.h>

// Circuit: 4-layer sum-product network, real semiring.
// L0: prod (binary fan-in) over virtual input x = [0, 1, pos0, neg0, ...]
// L1: segment-sum (sorted ix_out), 8M edges -> 1M segs
// L2: prod (binary fan-in)
// L3: segment-sum (sorted ix_out), 1M edges -> 125k segs
//
// R13: per-REQUEST cost model (R11/R12 falsified per-instruction model):
// scattered lane-requests cost ~4.5cyc each regardless of instruction
// packing or L2 hit (R9: 16 quarter-density gathers = R12: 4 full-density
// = ~256 req/slot = ~80us). L1 and L0 each carry ~8M compulsory scattered
// requests (~65-80us each); remaining ~100us of the 266 is dispatch
// overhead across 5 dispatches. So:
//  - 5 dispatches -> 3: drop init (L0 gathers x_pos f32 directly, absorbs
//    y1/out zeroing); fuse L2 into L3 (same request count, y2 never
//    materialized).
//  - L1: exact revert to R9's proven 4-window convoy (79.8us best).

#define PERS_BLOCKS 2048
#define PERS_THREADS 256
#define WBITS_H 20     // 1M halfs = 2MB window

typedef __attribute__((ext_vector_type(4))) int   iv4;
typedef __attribute__((ext_vector_type(4))) float fv4;
typedef __attribute__((ext_vector_type(4))) unsigned int uv4;

__device__ __forceinline__ iv4 nt_load4(const int* p) {
    return __builtin_nontemporal_load((const iv4*)p);
}

// ---------- L0: 8 products/thread, direct f32 gathers + zeroing ----------
__device__ __forceinline__ float decode32(const float* __restrict__ xp, int idx) {
    int k = (idx - 2) >> 1;
    k = k < 0 ? 0 : k;                 // safe unconditional load (ILP)
    float v = xp[k];
    v = (idx & 1) ? 1.0f - v : v;
    if (idx < 2) v = (float)idx;       // constants override
    return v;
}

__global__ void layer0_prod8_zero_kernel(const float* __restrict__ xp,
                                         const int* __restrict__ ix,
                                         unsigned int* __restrict__ out16,
                                         float* __restrict__ y1,
                                         float* __restrict__ outv,
                                         int nT, int nz1, int nzo) {
    int t = blockIdx.x * blockDim.x + threadIdx.x;
    if (t < nz1) {   // zero y1 (float4 quads)
        fv4 z = {0.f, 0.f, 0.f, 0.f};
        __builtin_nontemporal_store(z, (fv4*)(y1 + 4 * (size_t)t));
    }
    if (t < nzo) {   // zero out (float4 quads)
        fv4 z = {0.f, 0.f, 0.f, 0.f};
        __builtin_nontemporal_store(z, (fv4*)(outv + 4 * (size_t)t));
    }
    if (t >= nT) return;
    iv4 p0 = nt_load4(ix + 16 * (size_t)t);
    iv4 p1 = nt_load4(ix + 16 * (size_t)t + 4);
    iv4 p2 = nt_load4(ix + 16 * (size_t)t + 8);
    iv4 p3 = nt_load4(ix + 16 * (size_t)t + 12);
    float a0 = decode32(xp, p0.x), b0 = decode32(xp, p0.y);
    float a1 = decode32(xp, p0.z), b1 = decode32(xp, p0.w);
    float a2 = decode32(xp, p1.x), b2 = decode32(xp, p1.y);
    float a3 = decode32(xp, p1.z), b3 = decode32(xp, p1.w);
    float a4 = decode32(xp, p2.x), b4 = decode32(xp, p2.y);
    float a5 = decode32(xp, p2.z), b5 = decode32(xp, p2.w);
    float a6 = decode32(xp, p3.x), b6 = decode32(xp, p3.y);
    float a7 = decode32(xp, p3.z), b7 = decode32(xp, p3.w);
    __half2 h0 = __floats2half2_rn(a0 * b0, a1 * b1);
    __half2 h1 = __floats2half2_rn(a2 * b2, a3 * b3);
    __half2 h2 = __floats2half2_rn(a4 * b4, a5 * b5);
    __half2 h3 = __floats2half2_rn(a6 * b6, a7 * b7);
    uv4 r;
    r.x = *(const unsigned int*)&h0;
    r.y = *(const unsigned int*)&h1;
    r.z = *(const unsigned int*)&h2;
    r.w = *(const unsigned int*)&h3;
    __builtin_nontemporal_store(r, (uv4*)(out16 + 4 * (size_t)t));
}

// ---------- L1: sum over fp16 source, window-outer convoy (R9) ----------
template<int NS, int NWIN>
__global__ __launch_bounds__(PERS_THREADS)
void sum_win_h_kernel(const __half* __restrict__ vin,
                      const int* __restrict__ ix_in,
                      const int* __restrict__ ix_out,
                      float* __restrict__ out, int nT4) {
    const int nTh  = gridDim.x * blockDim.x;
    const int gtid = blockIdx.x * blockDim.x + threadIdx.x;
    const int lane = threadIdx.x & 63;

    iv4    a[NS];
    iv4    sg[NS];
    float4 v[NS];
    bool   act[NS];
    #pragma unroll
    for (int s = 0; s < NS; ++s) {
        int t = s * nTh + gtid;
        act[s] = (t < nT4);
        if (act[s]) {
            a[s]  = nt_load4(ix_in  + 4 * (size_t)t);
            sg[s] = nt_load4(ix_out + 4 * (size_t)t);
        } else {
            a[s]  = (iv4){-1, -1, -1, -1};
            sg[s] = (iv4){-1, -1, -1, -1};
        }
        v[s] = make_float4(0.f, 0.f, 0.f, 0.f);
    }

    #pragma unroll
    for (int w = 0; w < NWIN; ++w) {
        #pragma unroll
        for (int s = 0; s < NS; ++s) {
            if ((a[s].x >> WBITS_H) == w) v[s].x = __half2float(vin[a[s].x]);
            if ((a[s].y >> WBITS_H) == w) v[s].y = __half2float(vin[a[s].y]);
            if ((a[s].z >> WBITS_H) == w) v[s].z = __half2float(vin[a[s].z]);
            if ((a[s].w >> WBITS_H) == w) v[s].w = __half2float(vin[a[s].w]);
        }
    }

    #pragma unroll
    for (int s = 0; s < NS; ++s) {
        int seg = -1; float val = 0.f;
        if (act[s]) {
            int cur = sg[s].x; float acc = v[s].x;
            if (sg[s].y == cur) acc += v[s].y; else { atomicAdd(&out[cur], acc); cur = sg[s].y; acc = v[s].y; }
            if (sg[s].z == cur) acc += v[s].z; else { atomicAdd(&out[cur], acc); cur = sg[s].z; acc = v[s].z; }
            if (sg[s].w == cur) acc += v[s].w; else { atomicAdd(&out[cur], acc); cur = sg[s].w; acc = v[s].w; }
            seg = cur; val = acc;
        }
        #pragma unroll
        for (int off = 1; off < 64; off <<= 1) {
            float vv = __shfl_up(val, off, 64);
            int   ss = __shfl_up(seg, off, 64);
            if (lane >= off && ss == seg) val += vv;
        }
        int seg_next = __shfl_down(seg, 1, 64);
        bool is_last = (lane == 63) || (seg_next != seg);
        if (act[s] && is_last) atomicAdd(&out[seg], val);
    }
}

// ---------- L2+L3 fused: prod through ix_in2, segment-sum to out ----------
__global__ void sum4_prod_f32_kernel(const float* __restrict__ y1,
                                     const int* __restrict__ ix2,
                                     const int* __restrict__ ix_in3,
                                     const int* __restrict__ ix_out3,
                                     float* __restrict__ out, int nT4) {
    int t = blockIdx.x * blockDim.x + threadIdx.x;
    int lane = threadIdx.x & 63;
    int seg = -1; float val = 0.f;
    if (t < nT4) {
        iv4 a  = nt_load4(ix_in3  + 4 * (size_t)t);
        iv4 sg = nt_load4(ix_out3 + 4 * (size_t)t);
        int2 q0 = *(const int2*)(ix2 + 2 * (size_t)a.x);
        int2 q1 = *(const int2*)(ix2 + 2 * (size_t)a.y);
        int2 q2 = *(const int2*)(ix2 + 2 * (size_t)a.z);
        int2 q3 = *(const int2*)(ix2 + 2 * (size_t)a.w);
        float v0 = y1[q0.x] * y1[q0.y];
        float v1 = y1[q1.x] * y1[q1.y];
        float v2 = y1[q2.x] * y1[q2.y];
        float v3 = y1[q3.x] * y1[q3.y];
        int cur = sg.x; float acc = v0;
        if (sg.y == cur) acc += v1; else { atomicAdd(&out[cur], acc); cur = sg.y; acc = v1; }
        if (sg.z == cur) acc += v2; else { atomicAdd(&out[cur], acc); cur = sg.z; acc = v2; }
        if (sg.w == cur) acc += v3; else { atomicAdd(&out[cur], acc); cur = sg.w; acc = v3; }
        seg = cur; val = acc;
    }
    #pragma unroll
    for (int off = 1; off < 64; off <<= 1) {
        float vv = __shfl_up(val, off, 64);
        int   ss = __shfl_up(seg, off, 64);
        if (lane >= off && ss == seg) val += vv;
    }
    int seg_next = __shfl_down(seg, 1, 64);
    bool is_last = (lane == 63) || (seg_next != seg);
    if (t < nT4 && is_last) atomicAdd(&out[seg], val);
}

extern "C" void kernel_launch(void* const* d_in, const int* in_sizes, int n_in,
                              void* d_out, int out_size, void* d_ws, size_t ws_size,
                              hipStream_t stream) {
    const float* x_pos  = (const float*)d_in[0];
    const int*   ix_in0 = (const int*)d_in[1];
    const int*   ix_in1 = (const int*)d_in[2];
    const int*   ix_out1= (const int*)d_in[3];
    const int*   ix_in2 = (const int*)d_in[4];
    const int*   ix_in3 = (const int*)d_in[5];
    const int*   ix_out3= (const int*)d_in[6];
    float* out = (float*)d_out;

    const int M0 = in_sizes[1] / 2;   // 4,000,000
    const int E1 = in_sizes[2];       // 8,000,000
    const int M1 = 1000000;
    const int E3 = in_sizes[5];       // 1,000,000
    const int M3 = out_size;          // 125,000

    char* ws = (char*)d_ws;
    __half* y0 = (__half*)(ws);                            //  8 MB
    float*  y1 = (float*)(ws + (size_t)8 * 1024 * 1024);   //  4 MB

    const int B = 256;

    // 1) L0: 500K threads x 8 products, direct f32 gathers; zero y1 + out
    int t0  = M0 / 8;          // 500,000
    int nz1 = M1 / 4;          // 250,000 float4 zeros for y1
    int nzo = M3 / 4;          //  31,250 float4 zeros for out
    layer0_prod8_zero_kernel<<<(t0 + B - 1) / B, B, 0, stream>>>(
        x_pos, ix_in0, (unsigned int*)y0, y1, out, t0, nz1, nzo);

    // 2) L1: fp16 source 8MB -> 4 x 2MB windows, convoy, NS=4 covers 2M slots
    int t1 = E1 / 4;
    sum_win_h_kernel<4, 4><<<PERS_BLOCKS, PERS_THREADS, 0, stream>>>(
        y0, ix_in1, ix_out1, y1, t1);

    // 3) L2+L3 fused: prod via ix_in2 pairs, segment-sum to out
    int t3 = E3 / 4;
    sum4_prod_f32_kernel<<<(t3 + B - 1) / B, B, 0, stream>>>(
        y1, ix_in2, ix_in3, ix_out3, out, t3);
}

// Round 5
// 260.744 us; speedup vs baseline: 1.1031x; 1.1031x over previous
//
#include <hip/hip_runtime.h>
#include <hip/hip_fp16.h>

// Circuit: 4-layer sum-product network, real semiring.
// L0: prod (binary fan-in) over virtual input x = [0, 1, pos0, neg0, ...]
// L1: segment-sum (sorted ix_out), 8M edges -> 1M segs
// L2: prod (binary fan-in)
// L3: segment-sum (sorted ix_out), 1M edges -> 125k segs
//
// R14: best-of-all-rounds recombination under the consolidated model:
//   time ~ scattered-request-count x ~4cyc (independent of instruction
//   packing [R11/R12] and cache hit level [R9 87MB == R12 279MB == 80us]),
//   PLUS an HBM-traffic term when FETCH exceeds ~3.5TB/s (R13 L0 f32:
//   265MB = 74us traffic-bound), PLUS ~100us fixed per-iteration overhead
//   that does NOT scale with dispatch count (R13: 3 disp, no gain).
//  - init restored: fp16 cvt (4MB table => L2-resident, 2B gathers) + both
//    zeroings folded in. R13's f32 direct gather cost L0 +25-30us.
//  - L0: proven prod8 fp16 (R9).
//  - L1: proven R9 4-window convoy verbatim (79.8us best measured).
//  - L2+L3 kept fused (R13): +1M scattered requests but -1 dispatch.

#define PERS_BLOCKS 2048
#define PERS_THREADS 256
#define WBITS_H 20     // 1M halfs = 2MB window

typedef __attribute__((ext_vector_type(4))) int   iv4;
typedef __attribute__((ext_vector_type(4))) float fv4;
typedef __attribute__((ext_vector_type(4))) unsigned int uv4;

__device__ __forceinline__ iv4 nt_load4(const int* p) {
    return __builtin_nontemporal_load((const iv4*)p);
}

// ---------- init: cvt x_pos f32 -> fp16 table, zero y1 and out ----------
__global__ void init_kernel(const float* __restrict__ in, unsigned int* __restrict__ x16,
                            float* __restrict__ y1, float* __restrict__ out,
                            int n4, int nz1, int nzo) {
    int t = blockIdx.x * blockDim.x + threadIdx.x;
    if (t < n4) {
        fv4 f = __builtin_nontemporal_load((const fv4*)(in + 4 * (size_t)t));
        __half2 lo = __floats2half2_rn(f.x, f.y);
        __half2 hi = __floats2half2_rn(f.z, f.w);
        unsigned int rlo = *(const unsigned int*)&lo;
        unsigned int rhi = *(const unsigned int*)&hi;
        x16[2 * t]     = rlo;
        x16[2 * t + 1] = rhi;
    }
    if (t < nz1) {   // zero y1
        fv4 z = {0.f, 0.f, 0.f, 0.f};
        __builtin_nontemporal_store(z, (fv4*)(y1 + 4 * (size_t)t));
    }
    if (t < nzo) {   // zero out
        fv4 z = {0.f, 0.f, 0.f, 0.f};
        __builtin_nontemporal_store(z, (fv4*)(out + 4 * (size_t)t));
    }
}

// ---------- L0: 8 products/thread, straight gathers from fp16 table -------
__device__ __forceinline__ float decode16(const __half* __restrict__ xp, int idx) {
    int k = (idx - 2) >> 1;
    k = k < 0 ? 0 : k;                 // safe unconditional load (ILP)
    float v = __half2float(xp[k]);
    v = (idx & 1) ? 1.0f - v : v;
    if (idx < 2) v = (float)idx;       // constants override
    return v;
}

__global__ void layer0_prod8_kernel(const __half* __restrict__ x16,
                                    const int* __restrict__ ix,
                                    unsigned int* __restrict__ out16, int nT) {
    int t = blockIdx.x * blockDim.x + threadIdx.x;
    if (t >= nT) return;
    iv4 p0 = nt_load4(ix + 16 * (size_t)t);
    iv4 p1 = nt_load4(ix + 16 * (size_t)t + 4);
    iv4 p2 = nt_load4(ix + 16 * (size_t)t + 8);
    iv4 p3 = nt_load4(ix + 16 * (size_t)t + 12);
    float a0 = decode16(x16, p0.x), b0 = decode16(x16, p0.y);
    float a1 = decode16(x16, p0.z), b1 = decode16(x16, p0.w);
    float a2 = decode16(x16, p1.x), b2 = decode16(x16, p1.y);
    float a3 = decode16(x16, p1.z), b3 = decode16(x16, p1.w);
    float a4 = decode16(x16, p2.x), b4 = decode16(x16, p2.y);
    float a5 = decode16(x16, p2.z), b5 = decode16(x16, p2.w);
    float a6 = decode16(x16, p3.x), b6 = decode16(x16, p3.y);
    float a7 = decode16(x16, p3.z), b7 = decode16(x16, p3.w);
    __half2 h0 = __floats2half2_rn(a0 * b0, a1 * b1);
    __half2 h1 = __floats2half2_rn(a2 * b2, a3 * b3);
    __half2 h2 = __floats2half2_rn(a4 * b4, a5 * b5);
    __half2 h3 = __floats2half2_rn(a6 * b6, a7 * b7);
    uv4 r;
    r.x = *(const unsigned int*)&h0;
    r.y = *(const unsigned int*)&h1;
    r.z = *(const unsigned int*)&h2;
    r.w = *(const unsigned int*)&h3;
    __builtin_nontemporal_store(r, (uv4*)(out16 + 4 * (size_t)t));
}

// ---------- L1: sum over fp16 source, window-outer convoy (R9) ----------
template<int NS, int NWIN>
__global__ __launch_bounds__(PERS_THREADS)
void sum_win_h_kernel(const __half* __restrict__ vin,
                      const int* __restrict__ ix_in,
                      const int* __restrict__ ix_out,
                      float* __restrict__ out, int nT4) {
    const int nTh  = gridDim.x * blockDim.x;
    const int gtid = blockIdx.x * blockDim.x + threadIdx.x;
    const int lane = threadIdx.x & 63;

    iv4    a[NS];
    iv4    sg[NS];
    float4 v[NS];
    bool   act[NS];
    #pragma unroll
    for (int s = 0; s < NS; ++s) {
        int t = s * nTh + gtid;
        act[s] = (t < nT4);
        if (act[s]) {
            a[s]  = nt_load4(ix_in  + 4 * (size_t)t);
            sg[s] = nt_load4(ix_out + 4 * (size_t)t);
        } else {
            a[s]  = (iv4){-1, -1, -1, -1};
            sg[s] = (iv4){-1, -1, -1, -1};
        }
        v[s] = make_float4(0.f, 0.f, 0.f, 0.f);
    }

    #pragma unroll
    for (int w = 0; w < NWIN; ++w) {
        #pragma unroll
        for (int s = 0; s < NS; ++s) {
            if ((a[s].x >> WBITS_H) == w) v[s].x = __half2float(vin[a[s].x]);
            if ((a[s].y >> WBITS_H) == w) v[s].y = __half2float(vin[a[s].y]);
            if ((a[s].z >> WBITS_H) == w) v[s].z = __half2float(vin[a[s].z]);
            if ((a[s].w >> WBITS_H) == w) v[s].w = __half2float(vin[a[s].w]);
        }
    }

    #pragma unroll
    for (int s = 0; s < NS; ++s) {
        int seg = -1; float val = 0.f;
        if (act[s]) {
            int cur = sg[s].x; float acc = v[s].x;
            if (sg[s].y == cur) acc += v[s].y; else { atomicAdd(&out[cur], acc); cur = sg[s].y; acc = v[s].y; }
            if (sg[s].z == cur) acc += v[s].z; else { atomicAdd(&out[cur], acc); cur = sg[s].z; acc = v[s].z; }
            if (sg[s].w == cur) acc += v[s].w; else { atomicAdd(&out[cur], acc); cur = sg[s].w; acc = v[s].w; }
            seg = cur; val = acc;
        }
        #pragma unroll
        for (int off = 1; off < 64; off <<= 1) {
            float vv = __shfl_up(val, off, 64);
            int   ss = __shfl_up(seg, off, 64);
            if (lane >= off && ss == seg) val += vv;
        }
        int seg_next = __shfl_down(seg, 1, 64);
        bool is_last = (lane == 63) || (seg_next != seg);
        if (act[s] && is_last) atomicAdd(&out[seg], val);
    }
}

// ---------- L2+L3 fused: prod through ix_in2, segment-sum to out ----------
__global__ void sum4_prod_f32_kernel(const float* __restrict__ y1,
                                     const int* __restrict__ ix2,
                                     const int* __restrict__ ix_in3,
                                     const int* __restrict__ ix_out3,
                                     float* __restrict__ out, int nT4) {
    int t = blockIdx.x * blockDim.x + threadIdx.x;
    int lane = threadIdx.x & 63;
    int seg = -1; float val = 0.f;
    if (t < nT4) {
        iv4 a  = nt_load4(ix_in3  + 4 * (size_t)t);
        iv4 sg = nt_load4(ix_out3 + 4 * (size_t)t);
        int2 q0 = *(const int2*)(ix2 + 2 * (size_t)a.x);
        int2 q1 = *(const int2*)(ix2 + 2 * (size_t)a.y);
        int2 q2 = *(const int2*)(ix2 + 2 * (size_t)a.z);
        int2 q3 = *(const int2*)(ix2 + 2 * (size_t)a.w);
        float v0 = y1[q0.x] * y1[q0.y];
        float v1 = y1[q1.x] * y1[q1.y];
        float v2 = y1[q2.x] * y1[q2.y];
        float v3 = y1[q3.x] * y1[q3.y];
        int cur = sg.x; float acc = v0;
        if (sg.y == cur) acc += v1; else { atomicAdd(&out[cur], acc); cur = sg.y; acc = v1; }
        if (sg.z == cur) acc += v2; else { atomicAdd(&out[cur], acc); cur = sg.z; acc = v2; }
        if (sg.w == cur) acc += v3; else { atomicAdd(&out[cur], acc); cur = sg.w; acc = v3; }
        seg = cur; val = acc;
    }
    #pragma unroll
    for (int off = 1; off < 64; off <<= 1) {
        float vv = __shfl_up(val, off, 64);
        int   ss = __shfl_up(seg, off, 64);
        if (lane >= off && ss == seg) val += vv;
    }
    int seg_next = __shfl_down(seg, 1, 64);
    bool is_last = (lane == 63) || (seg_next != seg);
    if (t < nT4 && is_last) atomicAdd(&out[seg], val);
}

extern "C" void kernel_launch(void* const* d_in, const int* in_sizes, int n_in,
                              void* d_out, int out_size, void* d_ws, size_t ws_size,
                              hipStream_t stream) {
    const float* x_pos  = (const float*)d_in[0];
    const int*   ix_in0 = (const int*)d_in[1];
    const int*   ix_in1 = (const int*)d_in[2];
    const int*   ix_out1= (const int*)d_in[3];
    const int*   ix_in2 = (const int*)d_in[4];
    const int*   ix_in3 = (const int*)d_in[5];
    const int*   ix_out3= (const int*)d_in[6];
    float* out = (float*)d_out;

    const int NV = in_sizes[0];       // 2,000,000
    const int M0 = in_sizes[1] / 2;   // 4,000,000
    const int E1 = in_sizes[2];       // 8,000,000
    const int M1 = 1000000;
    const int E3 = in_sizes[5];       // 1,000,000
    const int M3 = out_size;          // 125,000

    char* ws = (char*)d_ws;
    __half* y0  = (__half*)(ws);                            //  8 MB
    float*  y1  = (float*)(ws + (size_t)8  * 1024 * 1024);  //  4 MB
    __half* x16 = (__half*)(ws + (size_t)12 * 1024 * 1024); //  4 MB

    const int B = 256;

    // 1) init: cvt x_pos -> fp16 table + zero y1 + zero out (one dispatch)
    int n4  = NV / 4;          // 500,000 cvt quads
    int nz1 = M1 / 4;          // 250,000 float4 zeros for y1
    int nzo = M3 / 4;          //  31,250 float4 zeros for out
    init_kernel<<<(n4 + B - 1) / B, B, 0, stream>>>(
        x_pos, (unsigned int*)x16, y1, out, n4, nz1, nzo);

    // 2) L0: 500K threads x 8 products, straight gathers from 4MB table
    int t0 = M0 / 8;
    layer0_prod8_kernel<<<(t0 + B - 1) / B, B, 0, stream>>>(
        x16, ix_in0, (unsigned int*)y0, t0);

    // 3) L1: fp16 source 8MB -> 4 x 2MB windows, convoy, NS=4 covers 2M slots
    int t1 = E1 / 4;
    sum_win_h_kernel<4, 4><<<PERS_BLOCKS, PERS_THREADS, 0, stream>>>(
        y0, ix_in1, ix_out1, y1, t1);

    // 4) L2+L3 fused: prod via ix_in2 pairs, segment-sum to out
    int t3 = E3 / 4;
    sum4_prod_f32_kernel<<<(t3 + B - 1) / B, B, 0, stream>>>(
        y1, ix_in2, ix_in3, ix_out3, out, t3);
}

// Round 6
// 254.301 us; speedup vs baseline: 1.1310x; 1.0253x over previous
//
#include <hip/hip_runtime.h>
#include <hip/hip_fp16.h>

// Circuit: 4-layer sum-product network, real semiring.
// L0: prod (binary fan-in) over virtual input x = [0, 1, pos0, neg0, ...]
// L1: segment-sum (sorted ix_out), 8M edges -> 1M segs
// L2: prod (binary fan-in)
// L3: segment-sum (sorted ix_out), 1M edges -> 125k segs
//
// R15: exact R9 structure restored (best harness-verified: 252.6us).
// R14 isolated the L2/L3 fusion as a ~+15us regression: same scattered-
// request count but a 3-deep serial gather chain on only ~15 waves/CU is
// latency-exposed; two shallow independent passes hide better.
//
// Session cost model (validated R9-R14):
//  - scattered lane-requests are the currency: ~3-4 cyc/request/CU service
//    rate, independent of instruction packing (R11/R12) and of cache hit
//    tier (R9 87MB FETCH == R12 279MB FETCH == ~same time);
//  - HBM-traffic term only when FETCH pushes >3.5TB/s (R13 f32 L0);
//  - ~105us fixed per-iteration residual, invariant to dispatch count
//    (3->7 dispatches), i.e. harness-side.
// Compulsory scattered requests: L0 9.5M + L1 10M + L2/L3 3.5M ~= 23M
// => ~155us kernel time; measured sum ~153us. We are at this floor.

#define PERS_BLOCKS 2048
#define PERS_THREADS 256
#define WBITS_H 20     // 1M halfs = 2MB window

typedef __attribute__((ext_vector_type(4))) int   iv4;
typedef __attribute__((ext_vector_type(4))) float fv4;
typedef __attribute__((ext_vector_type(4))) unsigned int uv4;

__device__ __forceinline__ iv4 nt_load4(const int* p) {
    return __builtin_nontemporal_load((const iv4*)p);
}

// ---------- init: cvt x_pos f32 -> fp16 table, zero y1 and out ----------
__global__ void init_kernel(const float* __restrict__ in, unsigned int* __restrict__ x16,
                            float* __restrict__ y1, float* __restrict__ out,
                            int n4, int nz1, int nzo) {
    int t = blockIdx.x * blockDim.x + threadIdx.x;
    if (t < n4) {
        fv4 f = __builtin_nontemporal_load((const fv4*)(in + 4 * (size_t)t));
        __half2 lo = __floats2half2_rn(f.x, f.y);
        __half2 hi = __floats2half2_rn(f.z, f.w);
        unsigned int rlo = *(const unsigned int*)&lo;
        unsigned int rhi = *(const unsigned int*)&hi;
        x16[2 * t]     = rlo;
        x16[2 * t + 1] = rhi;
    }
    if (t < nz1) {   // zero y1: nz1 float4 stores
        fv4 z = {0.f, 0.f, 0.f, 0.f};
        __builtin_nontemporal_store(z, (fv4*)(y1 + 4 * (size_t)t));
    }
    if (t < nzo) {   // zero out: nzo float4 stores
        fv4 z = {0.f, 0.f, 0.f, 0.f};
        __builtin_nontemporal_store(z, (fv4*)(out + 4 * (size_t)t));
    }
}

// ---------- L0: 8 products/thread, straight gathers from fp16 table -------
__device__ __forceinline__ float decode16(const __half* __restrict__ xp, int idx) {
    int k = (idx - 2) >> 1;
    k = k < 0 ? 0 : k;                 // safe unconditional load (ILP)
    float v = __half2float(xp[k]);
    v = (idx & 1) ? 1.0f - v : v;
    if (idx < 2) v = (float)idx;       // constants override
    return v;
}

__global__ void layer0_prod8_kernel(const __half* __restrict__ x16,
                                    const int* __restrict__ ix,
                                    unsigned int* __restrict__ out16, int nT) {
    int t = blockIdx.x * blockDim.x + threadIdx.x;
    if (t >= nT) return;
    iv4 p0 = nt_load4(ix + 16 * (size_t)t);
    iv4 p1 = nt_load4(ix + 16 * (size_t)t + 4);
    iv4 p2 = nt_load4(ix + 16 * (size_t)t + 8);
    iv4 p3 = nt_load4(ix + 16 * (size_t)t + 12);
    float a0 = decode16(x16, p0.x), b0 = decode16(x16, p0.y);
    float a1 = decode16(x16, p0.z), b1 = decode16(x16, p0.w);
    float a2 = decode16(x16, p1.x), b2 = decode16(x16, p1.y);
    float a3 = decode16(x16, p1.z), b3 = decode16(x16, p1.w);
    float a4 = decode16(x16, p2.x), b4 = decode16(x16, p2.y);
    float a5 = decode16(x16, p2.z), b5 = decode16(x16, p2.w);
    float a6 = decode16(x16, p3.x), b6 = decode16(x16, p3.y);
    float a7 = decode16(x16, p3.z), b7 = decode16(x16, p3.w);
    __half2 h0 = __floats2half2_rn(a0 * b0, a1 * b1);
    __half2 h1 = __floats2half2_rn(a2 * b2, a3 * b3);
    __half2 h2 = __floats2half2_rn(a4 * b4, a5 * b5);
    __half2 h3 = __floats2half2_rn(a6 * b6, a7 * b7);
    uv4 r;
    r.x = *(const unsigned int*)&h0;
    r.y = *(const unsigned int*)&h1;
    r.z = *(const unsigned int*)&h2;
    r.w = *(const unsigned int*)&h3;
    __builtin_nontemporal_store(r, (uv4*)(out16 + 4 * (size_t)t));
}

// ---------- L1: sum over fp16 source, window-outer convoy ----------
template<int NS, int NWIN>
__global__ __launch_bounds__(PERS_THREADS)
void sum_win_h_kernel(const __half* __restrict__ vin,
                      const int* __restrict__ ix_in,
                      const int* __restrict__ ix_out,
                      float* __restrict__ out, int nT4) {
    const int nTh  = gridDim.x * blockDim.x;
    const int gtid = blockIdx.x * blockDim.x + threadIdx.x;
    const int lane = threadIdx.x & 63;

    iv4    a[NS];
    iv4    sg[NS];
    float4 v[NS];
    bool   act[NS];
    #pragma unroll
    for (int s = 0; s < NS; ++s) {
        int t = s * nTh + gtid;
        act[s] = (t < nT4);
        if (act[s]) {
            a[s]  = nt_load4(ix_in  + 4 * (size_t)t);
            sg[s] = nt_load4(ix_out + 4 * (size_t)t);
        } else {
            a[s]  = (iv4){-1, -1, -1, -1};
            sg[s] = (iv4){-1, -1, -1, -1};
        }
        v[s] = make_float4(0.f, 0.f, 0.f, 0.f);
    }

    #pragma unroll
    for (int w = 0; w < NWIN; ++w) {
        #pragma unroll
        for (int s = 0; s < NS; ++s) {
            if ((a[s].x >> WBITS_H) == w) v[s].x = __half2float(vin[a[s].x]);
            if ((a[s].y >> WBITS_H) == w) v[s].y = __half2float(vin[a[s].y]);
            if ((a[s].z >> WBITS_H) == w) v[s].z = __half2float(vin[a[s].z]);
            if ((a[s].w >> WBITS_H) == w) v[s].w = __half2float(vin[a[s].w]);
        }
    }

    #pragma unroll
    for (int s = 0; s < NS; ++s) {
        int seg = -1; float val = 0.f;
        if (act[s]) {
            int cur = sg[s].x; float acc = v[s].x;
            if (sg[s].y == cur) acc += v[s].y; else { atomicAdd(&out[cur], acc); cur = sg[s].y; acc = v[s].y; }
            if (sg[s].z == cur) acc += v[s].z; else { atomicAdd(&out[cur], acc); cur = sg[s].z; acc = v[s].z; }
            if (sg[s].w == cur) acc += v[s].w; else { atomicAdd(&out[cur], acc); cur = sg[s].w; acc = v[s].w; }
            seg = cur; val = acc;
        }
        #pragma unroll
        for (int off = 1; off < 64; off <<= 1) {
            float vv = __shfl_up(val, off, 64);
            int   ss = __shfl_up(seg, off, 64);
            if (lane >= off && ss == seg) val += vv;
        }
        int seg_next = __shfl_down(seg, 1, 64);
        bool is_last = (lane == 63) || (seg_next != seg);
        if (act[s] && is_last) atomicAdd(&out[seg], val);
    }
}

// ---------- L3: sum over f32 source, single pass (small) ----------
__global__ void sum4_f32_kernel(const float* __restrict__ vin,
                                const int* __restrict__ ix_in,
                                const int* __restrict__ ix_out,
                                float* __restrict__ out, int nT4) {
    int t = blockIdx.x * blockDim.x + threadIdx.x;
    int lane = threadIdx.x & 63;
    int seg = -1; float val = 0.f;
    if (t < nT4) {
        iv4 a  = nt_load4(ix_in  + 4 * (size_t)t);
        iv4 sg = nt_load4(ix_out + 4 * (size_t)t);
        float v0 = vin[a.x], v1 = vin[a.y], v2 = vin[a.z], v3 = vin[a.w];
        int cur = sg.x; float acc = v0;
        if (sg.y == cur) acc += v1; else { atomicAdd(&out[cur], acc); cur = sg.y; acc = v1; }
        if (sg.z == cur) acc += v2; else { atomicAdd(&out[cur], acc); cur = sg.z; acc = v2; }
        if (sg.w == cur) acc += v3; else { atomicAdd(&out[cur], acc); cur = sg.w; acc = v3; }
        seg = cur; val = acc;
    }
    #pragma unroll
    for (int off = 1; off < 64; off <<= 1) {
        float vv = __shfl_up(val, off, 64);
        int   ss = __shfl_up(seg, off, 64);
        if (lane >= off && ss == seg) val += vv;
    }
    int seg_next = __shfl_down(seg, 1, 64);
    bool is_last = (lane == 63) || (seg_next != seg);
    if (t < nT4 && is_last) atomicAdd(&out[seg], val);
}

// ---------- L2: small product layer ----------
__global__ void prod2_kernel(const float* __restrict__ vin,
                             const int* __restrict__ ix,
                             float2* __restrict__ out, int nT) {
    int t = blockIdx.x * blockDim.x + threadIdx.x;
    if (t >= nT) return;
    iv4 p = nt_load4(ix + 4 * (size_t)t);
    float a0 = vin[p.x], b0 = vin[p.y];
    float a1 = vin[p.z], b1 = vin[p.w];
    float2 r; r.x = a0 * b0; r.y = a1 * b1;
    out[t] = r;
}

extern "C" void kernel_launch(void* const* d_in, const int* in_sizes, int n_in,
                              void* d_out, int out_size, void* d_ws, size_t ws_size,
                              hipStream_t stream) {
    const float* x_pos  = (const float*)d_in[0];
    const int*   ix_in0 = (const int*)d_in[1];
    const int*   ix_in1 = (const int*)d_in[2];
    const int*   ix_out1= (const int*)d_in[3];
    const int*   ix_in2 = (const int*)d_in[4];
    const int*   ix_in3 = (const int*)d_in[5];
    const int*   ix_out3= (const int*)d_in[6];
    float* out = (float*)d_out;

    const int NV = in_sizes[0];       // 2,000,000
    const int M0 = in_sizes[1] / 2;   // 4,000,000
    const int E1 = in_sizes[2];       // 8,000,000
    const int M1 = 1000000;
    const int M2 = in_sizes[4] / 2;   // 500,000
    const int E3 = in_sizes[5];       // 1,000,000
    const int M3 = out_size;          // 125,000

    char* ws = (char*)d_ws;
    __half* y0  = (__half*)(ws);                            //  8 MB
    float*  y1  = (float*)(ws + (size_t)8  * 1024 * 1024);  //  4 MB
    float*  y2  = (float*)(ws + (size_t)12 * 1024 * 1024);  //  2 MB
    __half* x16 = (__half*)(ws + (size_t)14 * 1024 * 1024); //  4 MB

    const int B = 256;

    // 1) init: cvt x_pos -> fp16 table + zero y1 + zero out (one dispatch)
    int n4  = NV / 4;          // 500,000 cvt quads
    int nz1 = M1 / 4;          // 250,000 float4 zeros for y1
    int nzo = M3 / 4;          //  31,250 float4 zeros for out
    init_kernel<<<(n4 + B - 1) / B, B, 0, stream>>>(
        x_pos, (unsigned int*)x16, y1, out, n4, nz1, nzo);

    // 2) L0: 500K threads x 8 products, straight gathers from 4MB table
    int t0 = M0 / 8;
    layer0_prod8_kernel<<<(t0 + B - 1) / B, B, 0, stream>>>(
        x16, ix_in0, (unsigned int*)y0, t0);

    // 3) L1: fp16 source 8MB -> 4 x 2MB windows, convoy, NS=4 covers 2M slots
    int t1 = E1 / 4;
    sum_win_h_kernel<4, 4><<<PERS_BLOCKS, PERS_THREADS, 0, stream>>>(
        y0, ix_in1, ix_out1, y1, t1);

    // 4) L2: y1 f32 4MB
    int t2 = M2 / 2;
    prod2_kernel<<<(t2 + B - 1) / B, B, 0, stream>>>(
        y1, ix_in2, (float2*)y2, t2);

    // 5) L3: y2 f32 2MB, single pass
    int t3 = E3 / 4;
    sum4_f32_kernel<<<(t3 + B - 1) / B, B, 0, stream>>>(
        y2, ix_in3, ix_out3, out, t3);
}